// Round 1
// 125.952 us; speedup vs baseline: 1.0385x; 1.0385x over previous
//
#include <hip/hip_runtime.h>

#define BS 16
#define NQ 200
#define NPTS 25
#define VOC 96
#define VOCP1 97
#define NGT 32
#define LSEQ 25
#define NCOL (BS*NGT)      // 512
#define NBQ (BS*NQ)        // 3200
#define KL_EPS 1e-6f
#define FOCAL_EPS 1e-8f

#define NB_LOGP NBQ                       // 3200 blocks: per-(b,q) logP
#define NB_SOFT VOC                       // 96 blocks: soft rows
#define NB_CDIST 400                      // 50 row-tiles x 8 col-tiles
#define NB_K1 (NB_LOGP + NB_SOFT + NB_CDIST)  // 3696

// ==========================================================================
// K1: three independent block families in one launch.
//   [0, 3200)      : logP rows (softmax over 97, mean over 25 pts, renorm, log)
//   [3200, 3296)   : soft[96,96] rows (0.85*I + 0.15*softmax(cos-sim))
//   [3296, 3696)   : 64x64 L1-cdist tiles + locally-recomputed cost_class
// cost_class is recomputed per cdist tile (64 rows x 25 pts, x8 redundancy)
// so no cross-family dependency exists.
// ==========================================================================
__global__ __launch_bounds__(256) void K1(
        const float* __restrict__ pred_logits,       // [NBQ, 25]
        const float* __restrict__ pred_ctrl,         // [NBQ, 50]
        const float* __restrict__ pred_text_logits,  // [NBQ, 25, 97]
        const float* __restrict__ tgt_ctrl,          // [512, 50]
        const float* __restrict__ centroids,         // [96, 256]
        float* __restrict__ logP,                    // [NBQ, 96]
        float* __restrict__ soft,                    // [96, 96]
        float* __restrict__ out)                     // [NBQ, 512]
{
    __shared__ __align__(16) float smem[64 * 52 * 2 + 64];   // 26.9 KB, aliased
    const int tid = threadIdx.x;
    const int bid = blockIdx.x;

    if (bid < NB_LOGP) {
        // ---------------- logP family ----------------
        const int bq = bid;
        float* s_buf    = smem;          // 2425
        float* s_invden = smem + 2432;   // 25
        float* s_part   = smem + 2464;   // 4

        const float* tl = pred_text_logits + (size_t)bq * NPTS * VOCP1;
        for (int i = tid; i < NPTS * VOCP1; i += 256)
            s_buf[i] = __expf(tl[i]);
        __syncthreads();

        const int grp = tid >> 5, sub = tid & 31;
        for (int p = grp; p < NPTS; p += 8) {
            float s = 0.f;
            for (int v = sub; v < VOCP1; v += 32) s += s_buf[p * VOCP1 + v];
            #pragma unroll
            for (int off = 16; off; off >>= 1) s += __shfl_xor(s, off, 32);
            if (sub == 0) s_invden[p] = 1.0f / s;
        }
        __syncthreads();

        float avg = 0.f;
        if (tid < VOC) {
            float a = 0.f;
            #pragma unroll
            for (int p = 0; p < NPTS; p++)
                a += s_buf[p * VOCP1 + tid] * s_invden[p];
            avg = a * (1.0f / NPTS);
        }
        float s = avg;
        #pragma unroll
        for (int off = 32; off; off >>= 1) s += __shfl_xor(s, off);
        const int wave = tid >> 6, lane = tid & 63;
        if (lane == 0) s_part[wave] = s;
        __syncthreads();
        float denom = s_part[0] + s_part[1] + s_part[2] + s_part[3]
                    + (float)VOC * KL_EPS;
        if (tid < VOC)
            logP[(size_t)bq * VOC + tid] = __logf((avg + KL_EPS) / denom);

    } else if (bid < NB_LOGP + NB_SOFT) {
        // ---------------- soft-row family ----------------
        const int i = bid - NB_LOGP;
        float4* s_c  = (float4*)smem;        // 64 float4 = row i of centroids
        float* s_part = smem + 256;          // 4
        if (tid < 64)
            s_c[tid] = ((const float4*)(centroids + (size_t)i * 256))[tid];
        __syncthreads();

        float e = 0.f;
        if (tid < VOC) {
            float dij = 0.f, djj = 0.f, dii = 0.f;
            const float4* cj = (const float4*)(centroids + (size_t)tid * 256);
            #pragma unroll 4
            for (int k = 0; k < 64; k++) {
                float4 b = cj[k];
                float4 a = s_c[k];
                dij += a.x * b.x + a.y * b.y + a.z * b.z + a.w * b.w;
                djj += b.x * b.x + b.y * b.y + b.z * b.z + b.w * b.w;
                dii += a.x * a.x + a.y * a.y + a.z * a.z + a.w * a.w;
            }
            float sim = dij * rsqrtf(dii * djj);
            e = __expf(sim);
        }
        float s = e;
        #pragma unroll
        for (int off = 32; off; off >>= 1) s += __shfl_xor(s, off);
        const int wave = tid >> 6, lane = tid & 63;
        if (lane == 0) s_part[wave] = s;
        __syncthreads();
        float den = s_part[0] + s_part[1] + s_part[2] + s_part[3];
        if (tid < VOC) {
            float v = 0.15f * e / den;
            if (tid == i) v += 0.85f;
            soft[i * VOC + tid] = v;
        }

    } else {
        // ---------------- cdist + cost_class family ----------------
        const int cid = bid - (NB_LOGP + NB_SOFT);
        const int r0  = (cid >> 3) * 64;
        const int c0  = (cid & 7) * 64;
        float (*s_p)[52] = (float (*)[52])smem;              // 64*52
        float (*s_t)[52] = (float (*)[52])(smem + 3328);     // 64*52
        float* s_cc = smem + 6656;                           // 64

        const float* pg = pred_ctrl + (size_t)r0 * 50;
        const float* tg = tgt_ctrl + (size_t)c0 * 50;
        for (int i = tid; i < 64 * 50; i += 256) {
            int r = i / 50, d = i - r * 50;
            s_p[r][d] = pg[i];
            s_t[r][d] = tg[i];
        }
        // cost_class for this tile's 64 rows: 4 threads/row
        {
            const int row4 = tid >> 2, q4 = tid & 3;
            float cc = 0.f;
            for (int p = q4; p < NPTS; p += 4) {
                float x  = pred_logits[(size_t)(r0 + row4) * NPTS + p];
                float pr = 1.f / (1.f + __expf(-x));
                float pos = 0.25f * (1.f - pr) * (1.f - pr) * (-__logf(pr + FOCAL_EPS));
                float neg = 0.75f * pr * pr * (-__logf(1.f - pr + FOCAL_EPS));
                cc += pos - neg;
            }
            cc += __shfl_xor(cc, 1, 4);
            cc += __shfl_xor(cc, 2, 4);
            if (q4 == 0) s_cc[row4] = cc * (1.0f / NPTS);
        }
        __syncthreads();

        const int tx = tid & 15;       // col group (cols tx+16j)
        const int ty = tid >> 4;       // row group (rows ty*4+i)
        float acc[4][4];
        #pragma unroll
        for (int i = 0; i < 4; i++)
            #pragma unroll
            for (int j = 0; j < 4; j++) acc[i][j] = 0.f;

        #pragma unroll
        for (int k = 0; k < 48; k += 4) {
            float4 p[4], t[4];
            #pragma unroll
            for (int i = 0; i < 4; i++) p[i] = *(const float4*)&s_p[ty * 4 + i][k];
            #pragma unroll
            for (int j = 0; j < 4; j++) t[j] = *(const float4*)&s_t[tx + 16 * j][k];
            #pragma unroll
            for (int i = 0; i < 4; i++)
                #pragma unroll
                for (int j = 0; j < 4; j++)
                    acc[i][j] += fabsf(p[i].x - t[j].x) + fabsf(p[i].y - t[j].y)
                               + fabsf(p[i].z - t[j].z) + fabsf(p[i].w - t[j].w);
        }
        {   // k = 48, 49
            float2 p[4], t[4];
            #pragma unroll
            for (int i = 0; i < 4; i++) p[i] = *(const float2*)&s_p[ty * 4 + i][48];
            #pragma unroll
            for (int j = 0; j < 4; j++) t[j] = *(const float2*)&s_t[tx + 16 * j][48];
            #pragma unroll
            for (int i = 0; i < 4; i++)
                #pragma unroll
                for (int j = 0; j < 4; j++)
                    acc[i][j] += fabsf(p[i].x - t[j].x) + fabsf(p[i].y - t[j].y);
        }

        #pragma unroll
        for (int i = 0; i < 4; i++) {
            const int row = ty * 4 + i;
            const float cc = s_cc[row];
            #pragma unroll
            for (int j = 0; j < 4; j++)
                out[(size_t)(r0 + row) * NCOL + c0 + tx + 16 * j] = acc[i][j] + cc;
        }
    }
}

// ==========================================================================
// K2: fused kB+kT. Each block (8 rows of one batch b) re-derives T/TlogT/lens
// for its batch from soft (37 KB, L2-resident across the 400 blocks), then
// adds the block-diagonal KL text cost via RMW on out.
// ==========================================================================
__global__ __launch_bounds__(256) void K2(
        const int* __restrict__ tgt_texts,   // [512, 25]
        const float* __restrict__ soft,      // [96, 96]
        const float* __restrict__ logP,      // [NBQ, 96]
        float* __restrict__ out)             // [NBQ, 512]
{
    const int r0  = blockIdx.x * 8;       // 8 | 200: no batch crossing
    const int b   = r0 / NQ;
    const int tid = threadIdx.x;
    __shared__ float s_soft[VOC * VOC];      // 36.9 KB
    __shared__ int   s_chars[NGT * LSEQ];
    __shared__ float s_lp[8][VOC];
    __shared__ float s_Tt[VOC][NGT + 1];     // transposed, padded
    __shared__ float s_tl[NGT];
    __shared__ int   s_len[NGT];

    for (int i = tid; i < VOC * VOC / 4; i += 256)
        ((float4*)s_soft)[i] = ((const float4*)soft)[i];
    for (int i = tid; i < NGT * LSEQ; i += 256)
        s_chars[i] = tgt_texts[b * NGT * LSEQ + i];
    for (int i = tid; i < 8 * VOC; i += 256)
        s_lp[i / VOC][i % VOC] = logP[(size_t)r0 * VOC + i];
    __syncthreads();

    // --- T / TlogT / lens for this batch's 32 gts ---
    const int grp = tid >> 5, sub = tid & 31;
    for (int g = grp; g < NGT; g += 8) {
        int len = 0;
        float a0 = 0.f, a1 = 0.f, a2 = 0.f;
        for (int l = 0; l < LSEQ; l++) {
            int t = s_chars[g * LSEQ + l];
            if (t != VOC) {
                len++;
                const float* sr = s_soft + t * VOC;
                a0 += sr[sub]; a1 += sr[sub + 32]; a2 += sr[sub + 64];
            }
        }
        float inv = 1.f / (float)(len > 0 ? len : 1);
        a0 *= inv; a1 *= inv; a2 *= inv;
        float s = a0 + a1 + a2;
        #pragma unroll
        for (int off = 16; off; off >>= 1) s += __shfl_xor(s, off, 32);
        float denom = s + (float)VOC * KL_EPS;
        float t0 = (a0 + KL_EPS) / denom;
        float t1 = (a1 + KL_EPS) / denom;
        float t2 = (a2 + KL_EPS) / denom;
        s_Tt[sub][g]      = t0;
        s_Tt[sub + 32][g] = t1;
        s_Tt[sub + 64][g] = t2;
        float tl = t0 * __logf(t0) + t1 * __logf(t1) + t2 * __logf(t2);
        #pragma unroll
        for (int off = 16; off; off >>= 1) tl += __shfl_xor(tl, off, 32);
        if (sub == 0) { s_tl[g] = tl; s_len[g] = len; }
    }
    __syncthreads();

    // --- KL dot + diagonal RMW ---
    const int g = tid & 31, rs = tid >> 5;
    float d = 0.f;
    #pragma unroll 8
    for (int v = 0; v < VOC; v++) d += s_lp[rs][v] * s_Tt[v][g];
    float val = (s_len[g] == 0) ? 100.f : (s_tl[g] - d);
    size_t o = (size_t)(r0 + rs) * NCOL + b * NGT + g;
    out[o] += val;
}

extern "C" void kernel_launch(void* const* d_in, const int* in_sizes, int n_in,
                              void* d_out, int out_size, void* d_ws, size_t ws_size,
                              hipStream_t stream) {
    const float* pred_logits = (const float*)d_in[0];
    const float* pred_ctrl   = (const float*)d_in[1];
    const float* pred_text   = (const float*)d_in[2];
    const float* tgt_ctrl    = (const float*)d_in[3];
    const int*   tgt_texts   = (const int*)d_in[4];
    const float* centroids   = (const float*)d_in[5];
    float* out = (float*)d_out;

    float* ws   = (float*)d_ws;
    float* logP = ws;                        // 3200*96
    float* soft = logP + (size_t)NBQ * VOC;  // 96*96

    K1<<<NB_K1, 256, 0, stream>>>(pred_logits, pred_ctrl, pred_text,
                                  tgt_ctrl, centroids, logP, soft, out);
    K2<<<400, 256, 0, stream>>>(tgt_texts, soft, logP, out);
}

// Round 2
// 115.633 us; speedup vs baseline: 1.1312x; 1.0892x over previous
//
#include <hip/hip_runtime.h>

#define BS 16
#define NQ 200
#define NPTS 25
#define VOC 96
#define VOCP1 97
#define NGT 32
#define LSEQ 25
#define NCOL (BS*NGT)      // 512
#define NBQ (BS*NQ)        // 3200
#define KL_EPS 1e-6f
#define FOCAL_EPS 1e-8f

#define NB_CDIST 400                      // 50 row-tiles x 8 col-tiles
#define NB_SOFT VOC                       // 96 blocks: soft rows
#define NB_LOGP NBQ                       // 3200 blocks: per-(b,q) logP
#define NB_K1 (NB_CDIST + NB_SOFT + NB_LOGP)  // 3696

// ==========================================================================
// K1: three independent block families in one launch, heavy-VALU cdist first
// so it overlaps the latency-bound logP flood.
//   [0, 400)       : 64x64 L1-cdist tiles + locally-recomputed cost_class
//   [400, 496)     : soft[96,96] rows (0.85*I + 0.15*softmax(cos-sim))
//   [496, 3696)    : logP rows — fully register-resident wave algorithm:
//                    wave w owns points p = w+4k; per point, lane holds
//                    v=lane and v=64+lane; 6-step shfl row-sum; renorm
//                    denominator via identity sum_{v<96} avg = (25-S96)/25.
//                    One barrier total (4x97 cross-wave combine).
// ==========================================================================
__global__ __launch_bounds__(256) void K1(
        const float* __restrict__ pred_logits,       // [NBQ, 25]
        const float* __restrict__ pred_ctrl,         // [NBQ, 50]
        const float* __restrict__ pred_text_logits,  // [NBQ, 25, 97]
        const float* __restrict__ tgt_ctrl,          // [512, 50]
        const float* __restrict__ centroids,         // [96, 256]
        float* __restrict__ logP,                    // [NBQ, 96]
        float* __restrict__ soft,                    // [96, 96]
        float* __restrict__ out)                     // [NBQ, 512]
{
    __shared__ __align__(16) float smem[64 * 52 * 2 + 64];   // 26.9 KB, aliased
    const int tid = threadIdx.x;
    const int bid = blockIdx.x;

    if (bid < NB_CDIST) {
        // ---------------- cdist + cost_class family ----------------
        const int cid = bid;
        const int r0  = (cid >> 3) * 64;
        const int c0  = (cid & 7) * 64;
        float (*s_p)[52] = (float (*)[52])smem;              // 64*52
        float (*s_t)[52] = (float (*)[52])(smem + 3328);     // 64*52
        float* s_cc = smem + 6656;                           // 64

        const float* pg = pred_ctrl + (size_t)r0 * 50;
        const float* tg = tgt_ctrl + (size_t)c0 * 50;
        for (int i = tid; i < 64 * 50; i += 256) {
            int r = i / 50, d = i - r * 50;
            s_p[r][d] = pg[i];
            s_t[r][d] = tg[i];
        }
        // cost_class for this tile's 64 rows: 4 threads/row
        {
            const int row4 = tid >> 2, q4 = tid & 3;
            float cc = 0.f;
            for (int p = q4; p < NPTS; p += 4) {
                float x  = pred_logits[(size_t)(r0 + row4) * NPTS + p];
                float pr = 1.f / (1.f + __expf(-x));
                float pos = 0.25f * (1.f - pr) * (1.f - pr) * (-__logf(pr + FOCAL_EPS));
                float neg = 0.75f * pr * pr * (-__logf(1.f - pr + FOCAL_EPS));
                cc += pos - neg;
            }
            cc += __shfl_xor(cc, 1, 4);
            cc += __shfl_xor(cc, 2, 4);
            if (q4 == 0) s_cc[row4] = cc * (1.0f / NPTS);
        }
        __syncthreads();

        const int tx = tid & 15;       // col group (cols tx+16j)
        const int ty = tid >> 4;       // row group (rows ty*4+i)
        float acc[4][4];
        #pragma unroll
        for (int i = 0; i < 4; i++)
            #pragma unroll
            for (int j = 0; j < 4; j++) acc[i][j] = 0.f;

        #pragma unroll
        for (int k = 0; k < 48; k += 4) {
            float4 p[4], t[4];
            #pragma unroll
            for (int i = 0; i < 4; i++) p[i] = *(const float4*)&s_p[ty * 4 + i][k];
            #pragma unroll
            for (int j = 0; j < 4; j++) t[j] = *(const float4*)&s_t[tx + 16 * j][k];
            #pragma unroll
            for (int i = 0; i < 4; i++)
                #pragma unroll
                for (int j = 0; j < 4; j++)
                    acc[i][j] += fabsf(p[i].x - t[j].x) + fabsf(p[i].y - t[j].y)
                               + fabsf(p[i].z - t[j].z) + fabsf(p[i].w - t[j].w);
        }
        {   // k = 48, 49
            float2 p[4], t[4];
            #pragma unroll
            for (int i = 0; i < 4; i++) p[i] = *(const float2*)&s_p[ty * 4 + i][48];
            #pragma unroll
            for (int j = 0; j < 4; j++) t[j] = *(const float2*)&s_t[tx + 16 * j][48];
            #pragma unroll
            for (int i = 0; i < 4; i++)
                #pragma unroll
                for (int j = 0; j < 4; j++)
                    acc[i][j] += fabsf(p[i].x - t[j].x) + fabsf(p[i].y - t[j].y);
        }

        #pragma unroll
        for (int i = 0; i < 4; i++) {
            const int row = ty * 4 + i;
            const float cc = s_cc[row];
            #pragma unroll
            for (int j = 0; j < 4; j++)
                out[(size_t)(r0 + row) * NCOL + c0 + tx + 16 * j] = acc[i][j] + cc;
        }

    } else if (bid < NB_CDIST + NB_SOFT) {
        // ---------------- soft-row family ----------------
        const int i = bid - NB_CDIST;
        float4* s_c  = (float4*)smem;        // 64 float4 = row i of centroids
        float* s_part = smem + 256;          // 4
        if (tid < 64)
            s_c[tid] = ((const float4*)(centroids + (size_t)i * 256))[tid];
        __syncthreads();

        float e = 0.f;
        if (tid < VOC) {
            float dij = 0.f, djj = 0.f, dii = 0.f;
            const float4* cj = (const float4*)(centroids + (size_t)tid * 256);
            #pragma unroll 4
            for (int k = 0; k < 64; k++) {
                float4 b = cj[k];
                float4 a = s_c[k];
                dij += a.x * b.x + a.y * b.y + a.z * b.z + a.w * b.w;
                djj += b.x * b.x + b.y * b.y + b.z * b.z + b.w * b.w;
                dii += a.x * a.x + a.y * a.y + a.z * a.z + a.w * a.w;
            }
            float sim = dij * rsqrtf(dii * djj);
            e = __expf(sim);
        }
        float s = e;
        #pragma unroll
        for (int off = 32; off; off >>= 1) s += __shfl_xor(s, off);
        const int wave = tid >> 6, lane = tid & 63;
        if (lane == 0) s_part[wave] = s;
        __syncthreads();
        float den = s_part[0] + s_part[1] + s_part[2] + s_part[3];
        if (tid < VOC) {
            float v = 0.15f * e / den;
            if (tid == i) v += 0.85f;
            soft[i * VOC + tid] = v;
        }

    } else {
        // ---------------- logP family (register-resident) ----------------
        const int bq   = bid - (NB_CDIST + NB_SOFT);
        const int wave = tid >> 6, lane = tid & 63;
        float* s_acc = smem;          // [4][97]
        float* s_p96 = smem + 388;    // [4]

        const float* tl = pred_text_logits + (size_t)bq * NPTS * VOCP1;

        // batch-issue all loads: points p = wave + 4k (k<6), wave0 extra p=24
        float e0[7], e1[7];
        #pragma unroll
        for (int k = 0; k < 6; k++) {
            const float* row = tl + (size_t)(wave + 4 * k) * VOCP1;
            e0[k] = row[lane];
            e1[k] = (lane < 33) ? row[64 + lane] : 0.f;
        }
        if (wave == 0) {
            const float* row = tl + (size_t)24 * VOCP1;
            e0[6] = row[lane];
            e1[6] = (lane < 33) ? row[64 + lane] : 0.f;
        }

        float acc0 = 0.f, acc1 = 0.f, acc96 = 0.f;
        #pragma unroll
        for (int k = 0; k < 6; k++) {
            float a = __expf(e0[k]);
            float b = (lane < 33) ? __expf(e1[k]) : 0.f;
            float s = a + b;
            #pragma unroll
            for (int off = 32; off; off >>= 1) s += __shfl_xor(s, off);
            float inv = __builtin_amdgcn_rcpf(s);
            acc0  += a * inv;
            acc1  += b * inv;
            acc96 += __shfl(b, 32) * inv;      // blank prob, uniform
        }
        if (wave == 0) {
            float a = __expf(e0[6]);
            float b = (lane < 33) ? __expf(e1[6]) : 0.f;
            float s = a + b;
            #pragma unroll
            for (int off = 32; off; off >>= 1) s += __shfl_xor(s, off);
            float inv = __builtin_amdgcn_rcpf(s);
            acc0  += a * inv;
            acc1  += b * inv;
            acc96 += __shfl(b, 32) * inv;
        }

        s_acc[wave * VOCP1 + lane] = acc0;
        if (lane < 33) s_acc[wave * VOCP1 + 64 + lane] = acc1;
        if (lane == 0) s_p96[wave] = acc96;
        __syncthreads();

        if (tid < VOC) {
            float a = (s_acc[tid] + s_acc[VOCP1 + tid]
                     + s_acc[2 * VOCP1 + tid] + s_acc[3 * VOCP1 + tid]) * (1.0f / NPTS);
            float S96 = s_p96[0] + s_p96[1] + s_p96[2] + s_p96[3];
            float denom = (25.0f - S96) * (1.0f / NPTS) + (float)VOC * KL_EPS;
            logP[(size_t)bq * VOC + tid] = __logf((a + KL_EPS) / denom);
        }
    }
}

// ==========================================================================
// K2: fused T-derivation + block-diagonal KL text cost (RMW on out).
// soft (37 KB) is read straight from L2 — it is resident across all 400
// blocks; dropping the LDS stage cuts LDS 56->19 KB (2->8 blocks/CU) and
// removes the serial staging phase.
// ==========================================================================
__global__ __launch_bounds__(256) void K2(
        const int* __restrict__ tgt_texts,   // [512, 25]
        const float* __restrict__ soft,      // [96, 96]
        const float* __restrict__ logP,      // [NBQ, 96]
        float* __restrict__ out)             // [NBQ, 512]
{
    const int r0  = blockIdx.x * 8;       // 8 | 200: no batch crossing
    const int b   = r0 / NQ;
    const int tid = threadIdx.x;
    __shared__ int   s_chars[NGT * LSEQ];
    __shared__ float s_lp[8][VOC];
    __shared__ float s_Tt[VOC][NGT + 1];     // transposed, padded
    __shared__ float s_tl[NGT];
    __shared__ int   s_len[NGT];

    for (int i = tid; i < NGT * LSEQ; i += 256)
        s_chars[i] = tgt_texts[b * NGT * LSEQ + i];
    for (int i = tid; i < 8 * VOC; i += 256)
        s_lp[i / VOC][i % VOC] = logP[(size_t)r0 * VOC + i];
    __syncthreads();

    // --- T / TlogT / lens for this batch's 32 gts (soft read from L2) ---
    const int grp = tid >> 5, sub = tid & 31;
    for (int g = grp; g < NGT; g += 8) {
        int len = 0;
        float a0 = 0.f, a1 = 0.f, a2 = 0.f;
        for (int l = 0; l < LSEQ; l++) {
            int t = s_chars[g * LSEQ + l];
            if (t != VOC) {
                len++;
                const float* sr = soft + t * VOC;
                a0 += sr[sub]; a1 += sr[sub + 32]; a2 += sr[sub + 64];
            }
        }
        float inv = 1.f / (float)(len > 0 ? len : 1);
        a0 *= inv; a1 *= inv; a2 *= inv;
        float s = a0 + a1 + a2;
        #pragma unroll
        for (int off = 16; off; off >>= 1) s += __shfl_xor(s, off, 32);
        float denom = s + (float)VOC * KL_EPS;
        float t0 = (a0 + KL_EPS) / denom;
        float t1 = (a1 + KL_EPS) / denom;
        float t2 = (a2 + KL_EPS) / denom;
        s_Tt[sub][g]      = t0;
        s_Tt[sub + 32][g] = t1;
        s_Tt[sub + 64][g] = t2;
        float tl = t0 * __logf(t0) + t1 * __logf(t1) + t2 * __logf(t2);
        #pragma unroll
        for (int off = 16; off; off >>= 1) tl += __shfl_xor(tl, off, 32);
        if (sub == 0) { s_tl[g] = tl; s_len[g] = len; }
    }
    __syncthreads();

    // --- KL dot + diagonal RMW ---
    const int g = tid & 31, rs = tid >> 5;
    float d = 0.f;
    #pragma unroll 8
    for (int v = 0; v < VOC; v++) d += s_lp[rs][v] * s_Tt[v][g];
    float val = (s_len[g] == 0) ? 100.f : (s_tl[g] - d);
    size_t o = (size_t)(r0 + rs) * NCOL + b * NGT + g;
    out[o] += val;
}

extern "C" void kernel_launch(void* const* d_in, const int* in_sizes, int n_in,
                              void* d_out, int out_size, void* d_ws, size_t ws_size,
                              hipStream_t stream) {
    const float* pred_logits = (const float*)d_in[0];
    const float* pred_ctrl   = (const float*)d_in[1];
    const float* pred_text   = (const float*)d_in[2];
    const float* tgt_ctrl    = (const float*)d_in[3];
    const int*   tgt_texts   = (const int*)d_in[4];
    const float* centroids   = (const float*)d_in[5];
    float* out = (float*)d_out;

    float* ws   = (float*)d_ws;
    float* logP = ws;                        // 3200*96
    float* soft = logP + (size_t)NBQ * VOC;  // 96*96

    K1<<<NB_K1, 256, 0, stream>>>(pred_logits, pred_ctrl, pred_text,
                                  tgt_ctrl, centroids, logP, soft, out);
    K2<<<400, 256, 0, stream>>>(tgt_texts, soft, logP, out);
}